// Round 7
// baseline (28.986 us; speedup 1.0000x reference)
//
#include <hip/hip_runtime.h>

#define BEV_H 150
#define BEV_W 150
#define NCAM  6
#define CC    128
#define FH    48
#define FW    88
#define IMG_Hf 480.0f
#define IMG_Wf 800.0f
#define NPTS  24
#define NPIX  (NCAM * FH * FW)
#define UNROLL 6

__device__ __forceinline__ float rdlanef(float x, int l) {
    return __uint_as_float((unsigned)__builtin_amdgcn_readlane((int)__float_as_uint(x), l));
}
__device__ __forceinline__ float bflo(unsigned x) { return __uint_as_float(x << 16); }
__device__ __forceinline__ float bfhi(unsigned x) { return __uint_as_float(x & 0xffff0000u); }

// ---- feat f32 -> bf16 (RNE) conversion into workspace ----
__global__ __launch_bounds__(256) void conv_bf16_kernel(
    const float* __restrict__ in, unsigned short* __restrict__ out16)
{
    const int i = blockIdx.x * 256 + threadIdx.x;
    const int n4 = NPIX * CC / 4;
    if (i < n4) {
        const float4 v = ((const float4*)in)[i];
        unsigned a = __float_as_uint(v.x), b = __float_as_uint(v.y);
        unsigned c = __float_as_uint(v.z), d = __float_as_uint(v.w);
        a = (a + 0x7fffu + ((a >> 16) & 1u)) >> 16;
        b = (b + 0x7fffu + ((b >> 16) & 1u)) >> 16;
        c = (c + 0x7fffu + ((c >> 16) & 1u)) >> 16;
        d = (d + 0x7fffu + ((d >> 16) & 1u)) >> 16;
        uint2 o; o.x = a | (b << 16); o.y = c | (d << 16);
        ((uint2*)out16)[i] = o;
    }
}

// ---- gather: one BEV cell per wave, 4 waves/block, deep load issue ----
__global__ __launch_bounds__(256) void bev_gather_kernel(
    const unsigned short* __restrict__ feat16,  // (NCAM, FH, FW, C) bf16
    const float* __restrict__ I_,
    const float* __restrict__ E_,
    const float* __restrict__ grid,
    float* __restrict__ out)
{
    const int tid  = threadIdx.x;
    const int lane = tid & 63;
    const int wv   = tid >> 6;

    // --- bijective XCD-chunked swizzle: nwg=5625 = 704 + 7*703 ---
    int p;
    {
        const int b = blockIdx.x;
        const int xcd = b & 7, ii = b >> 3;
        p = (xcd == 0) ? ii : (704 + (xcd - 1) * 703 + ii);
    }
    const int ph = p / 75, pw = p - ph * 75;   // 2x2 cell patch per block
    const int h  = ph * 2 + (wv >> 1);
    const int w  = pw * 2 + (wv & 1);
    const int q  = h * BEV_W + w;

    // --- early grid loads (lanes 0-23, overlap with l2i phase) ---
    float gx = 0.f, gy = 0.f, gz = 0.f;
    int n = 0;
    const bool act = (lane < NPTS);
    if (act) {
        n = lane >> 2;
        const int d = lane & 3;
        gx = grid[((d * 3 + 0) * BEV_H + h) * BEV_W + w];
        gy = grid[((d * 3 + 1) * BEV_H + h) * BEV_W + w];
        gz = grid[((d * 3 + 2) * BEV_H + h) * BEV_W + w];
    }

    // --- cooperative l2i = I @ E[:3,:] in LDS ---
    __shared__ __align__(16) float s_l2i[NCAM][12];
    if (tid < NCAM * 12) {
        const int nn = tid / 12, r = tid % 12;
        const int i = r >> 2, j = r & 3;
        float acc = 0.f;
        #pragma unroll
        for (int k = 0; k < 3; ++k)
            acc += I_[nn * 9 + i * 3 + k] * E_[nn * 16 + k * 4 + j];
        s_l2i[nn][r] = acc;
    }
    __syncthreads();

    // --- projection: lane t (<24) owns one (cam,depth) point of this cell ---
    int   iT = 0, iB = 0;
    float wTL = 0.f, wTR = 0.f, wBL = 0.f, wBR = 0.f;
    bool  m = false;

    if (act) {
        const float x = gx * 102.4f - 51.2f;
        const float y = gy * 102.4f - 51.2f;
        const float z = gz * 8.0f   - 5.0f;

        const float4 M0 = *(const float4*)&s_l2i[n][0];
        const float4 M1 = *(const float4*)&s_l2i[n][4];
        const float4 M2 = *(const float4*)&s_l2i[n][8];
        const float p0 = M0.x * x + M0.y * y + M0.z * z + M0.w;
        const float p1 = M1.x * x + M1.y * y + M1.z * z + M1.w;
        const float p2 = M2.x * x + M2.y * y + M2.z * z + M2.w;

        const float eps = 1e-5f;
        const float zc = fmaxf(p2, eps);
        const float u = (p0 / zc) * (1.0f / IMG_Wf);
        const float v = (p1 / zc) * (1.0f / IMG_Hf);
        m = (p2 > eps) && (u > 0.f) && (u < 1.f) && (v > 0.f) && (v < 1.f);

        const float px = u * (float)FW - 0.5f;
        const float py = v * (float)FH - 0.5f;
        const float fx0 = floorf(px), fy0 = floorf(py);
        const int x0 = (int)fx0, y0 = (int)fy0;
        const int x1 = x0 + 1,   y1 = y0 + 1;
        const float wx1 = px - fx0, wy1 = py - fy0;
        const float wx0 = 1.f - wx1, wy0 = 1.f - wy1;

        const bool vx0 = (x0 >= 0) && (x0 < FW);
        const bool vx1 = (x1 >= 0) && (x1 < FW);
        const bool vy0 = (y0 >= 0) && (y0 < FH);
        const bool vy1 = (y1 >= 0) && (y1 < FH);
        const int cx0 = min(max(x0, 0), FW - 1), cx1 = min(max(x1, 0), FW - 1);
        const int cy0 = min(max(y0, 0), FH - 1), cy1 = min(max(y1, 0), FH - 1);

        const float w0v = wx0 * wy0 * ((vx0 && vy0) ? 1.f : 0.f);
        const float w1v = wx1 * wy0 * ((vx1 && vy0) ? 1.f : 0.f);
        const float w2v = wx0 * wy1 * ((vx0 && vy1) ? 1.f : 0.f);
        const float w3v = wx1 * wy1 * ((vx1 && vy1) ? 1.f : 0.f);

        const int bx = min(max(x0, 0), FW - 2);
        wTL = ((cx0 == bx)     ? w0v : 0.f) + ((cx1 == bx)     ? w1v : 0.f);
        wTR = ((cx0 == bx + 1) ? w0v : 0.f) + ((cx1 == bx + 1) ? w1v : 0.f);
        wBL = ((cx0 == bx)     ? w2v : 0.f) + ((cx1 == bx)     ? w3v : 0.f);
        wBR = ((cx0 == bx + 1) ? w2v : 0.f) + ((cx1 == bx + 1) ? w3v : 0.f);

        const int base = n * FH * FW;
        iT = (base + cy0 * FW + bx) * CC;
        iB = (base + cy1 * FW + bx) * CC;
    }

    unsigned bal = (unsigned)(__ballot(m) & 0xFFFFFFull);
    const float cnt = fmaxf((float)__popc(bal), 1.f);

    // --- extract up to UNROLL entries (wave-uniform), dummies repeat e[0] ---
    int e[UNROLL]; float s[UNROLL];
    e[0] = bal ? (int)__builtin_ctz(bal) : 0;
    s[0] = bal ? 1.f : 0.f;
    bal &= bal - 1;
    #pragma unroll
    for (int k = 1; k < UNROLL; ++k) {
        e[k] = bal ? (int)__builtin_ctz(bal) : e[0];
        s[k] = bal ? 1.f : 0.f;
        bal &= bal - 1;
    }

    // --- issue all 2*UNROLL loads back-to-back ---
    // lane layout: col = lane>>5 (0 -> bx, 1 -> bx+1), 4 channels per lane
    const int loff = ((lane >> 5) * CC) + ((lane & 31) * 4);
    uint2 T[UNROLL], Bo[UNROLL];
    #pragma unroll
    for (int k = 0; k < UNROLL; ++k) {
        const int jT = __builtin_amdgcn_readlane(iT, e[k]) + loff;
        const int jB = __builtin_amdgcn_readlane(iB, e[k]) + loff;
        T[k]  = *(const uint2*)(feat16 + jT);
        Bo[k] = *(const uint2*)(feat16 + jB);
    }

    // --- consume ---
    float a0 = 0.f, a1 = 0.f, a2 = 0.f, a3 = 0.f;
    const bool hic = (lane >= 32);
    #pragma unroll
    for (int k = 0; k < UNROLL; ++k) {
        const float wT = s[k] * (hic ? rdlanef(wTR, e[k]) : rdlanef(wTL, e[k]));
        const float wB = s[k] * (hic ? rdlanef(wBR, e[k]) : rdlanef(wBL, e[k]));
        a0 += wT * bflo(T[k].x)  + wB * bflo(Bo[k].x);
        a1 += wT * bfhi(T[k].x)  + wB * bfhi(Bo[k].x);
        a2 += wT * bflo(T[k].y)  + wB * bflo(Bo[k].y);
        a3 += wT * bfhi(T[k].y)  + wB * bfhi(Bo[k].y);
    }

    // --- rare tail (valid points beyond UNROLL) ---
    while (bal) {
        const int et = (int)__builtin_ctz(bal);
        bal &= bal - 1;
        const int jT = __builtin_amdgcn_readlane(iT, et) + loff;
        const int jB = __builtin_amdgcn_readlane(iB, et) + loff;
        const uint2 t  = *(const uint2*)(feat16 + jT);
        const uint2 bb = *(const uint2*)(feat16 + jB);
        const float wT = hic ? rdlanef(wTR, et) : rdlanef(wTL, et);
        const float wB = hic ? rdlanef(wBR, et) : rdlanef(wBL, et);
        a0 += wT * bflo(t.x) + wB * bflo(bb.x);
        a1 += wT * bfhi(t.x) + wB * bfhi(bb.x);
        a2 += wT * bflo(t.y) + wB * bflo(bb.y);
        a3 += wT * bfhi(t.y) + wB * bfhi(bb.y);
    }

    // --- combine the two column-halves (lane l <-> l+32) ---
    a0 += __shfl_xor(a0, 32);
    a1 += __shfl_xor(a1, 32);
    a2 += __shfl_xor(a2, 32);
    a3 += __shfl_xor(a3, 32);

    if (lane < 32) {
        const float inv = 1.f / cnt;
        float4 o;
        o.x = a0 * inv; o.y = a1 * inv; o.z = a2 * inv; o.w = a3 * inv;
        *(float4*)(out + q * CC + 4 * lane) = o;
    }
}

extern "C" void kernel_launch(void* const* d_in, const int* in_sizes, int n_in,
                              void* d_out, int out_size, void* d_ws, size_t ws_size,
                              hipStream_t stream) {
    const float* feat = (const float*)d_in[0];
    const float* I_   = (const float*)d_in[1];
    const float* E_   = (const float*)d_in[2];
    const float* grid = (const float*)d_in[3];
    float* out        = (float*)d_out;

    unsigned short* f16 = (unsigned short*)d_ws;
    const int n4 = NPIX * CC / 4;
    conv_bf16_kernel<<<(n4 + 255) / 256, 256, 0, stream>>>(feat, f16);
    bev_gather_kernel<<<(BEV_H / 2) * (BEV_W / 2), 256, 0, stream>>>(
        f16, I_, E_, grid, out);
}

// Round 8
// 18.948 us; speedup vs baseline: 1.5297x; 1.5297x over previous
//
#include <hip/hip_runtime.h>

#define BEV_H 150
#define BEV_W 150
#define NCAM  6
#define CC    128
#define FH    48
#define FW    88
#define IMG_Hf 480.0f
#define IMG_Wf 800.0f
#define NPTS  24

__device__ __forceinline__ float rdlanef(float x, int l) {
    return __uint_as_float((unsigned)__builtin_amdgcn_readlane((int)__float_as_uint(x), l));
}

__global__ __launch_bounds__(128) void bev_sample_kernel(
    const float* __restrict__ feat,   // (NCAM, FH, FW, C)
    const float* __restrict__ I_,
    const float* __restrict__ E_,
    const float* __restrict__ grid,   // (D, 3, BEV_H, BEV_W)
    float* __restrict__ out)          // (Q, C)
{
    const int tid  = threadIdx.x;
    const int lane = tid & 63;
    const int wv   = tid >> 6;
    const int l32  = lane & 31;
    const bool lowhalf = (lane < 32);

    // --- 2D-compact XCD regions: 2 rows x 4 cols in 75x75 patch space.
    // region = blockIdx & 7 -> one XCD per region under round-robin dispatch.
    const int r    = blockIdx.x & 7;
    const int i    = blockIdx.x >> 3;
    const int row0 = (r < 4) ? 0 : 38;
    const int nrow = (r < 4) ? 38 : 37;
    const int c3   = r & 3;
    const int col0 = c3 * 19;
    const int wr   = (c3 == 3) ? 18 : 19;
    if (i >= nrow * wr) return;        // block-uniform; before any barrier
    int ph, pw;
    if (wr == 19) { ph = i / 19; pw = i - ph * 19; }
    else          { ph = i / 18; pw = i - ph * 18; }
    ph += row0; pw += col0;

    const int h  = ph * 2 + wv;
    const int wA = pw * 2;
    const int qA = h * BEV_W + wA;

    // --- early grid loads (overlap with l2i phase) ---
    const bool actA = (lane < NPTS);
    const bool actB = (lane >= 32) && (lane < 32 + NPTS);
    float gx = 0.f, gy = 0.f, gz = 0.f;
    int n = 0;
    if (actA || actB) {
        n = l32 >> 2;
        const int d = l32 & 3;
        const int wc = wA + (actB ? 1 : 0);
        gx = grid[((d * 3 + 0) * BEV_H + h) * BEV_W + wc];
        gy = grid[((d * 3 + 1) * BEV_H + h) * BEV_W + wc];
        gz = grid[((d * 3 + 2) * BEV_H + h) * BEV_W + wc];
    }

    // --- cooperative l2i = I @ E[:3,:] in LDS ---
    __shared__ __align__(16) float s_l2i[NCAM][12];
    if (tid < NCAM * 12) {
        const int nn = tid / 12, rr = tid % 12;
        const int ii = rr >> 2, j = rr & 3;
        float acc = 0.f;
        #pragma unroll
        for (int k = 0; k < 3; ++k)
            acc += I_[nn * 9 + ii * 3 + k] * E_[nn * 16 + k * 4 + j];
        s_l2i[nn][rr] = acc;
    }
    __syncthreads();

    // --- projection: lanes 0-23 = cell A, lanes 32-55 = cell B ---
    int   iT = 0, iB = 0;
    float wTL = 0.f, wTR = 0.f, wBL = 0.f, wBR = 0.f;
    bool  m = false;

    if (actA || actB) {
        const float x = gx * 102.4f - 51.2f;
        const float y = gy * 102.4f - 51.2f;
        const float z = gz * 8.0f   - 5.0f;

        const float4 M0 = *(const float4*)&s_l2i[n][0];
        const float4 M1 = *(const float4*)&s_l2i[n][4];
        const float4 M2 = *(const float4*)&s_l2i[n][8];
        const float p0 = M0.x * x + M0.y * y + M0.z * z + M0.w;
        const float p1 = M1.x * x + M1.y * y + M1.z * z + M1.w;
        const float p2 = M2.x * x + M2.y * y + M2.z * z + M2.w;

        const float eps = 1e-5f;
        const float zc = fmaxf(p2, eps);
        const float u = (p0 / zc) * (1.0f / IMG_Wf);
        const float v = (p1 / zc) * (1.0f / IMG_Hf);
        m = (p2 > eps) && (u > 0.f) && (u < 1.f) && (v > 0.f) && (v < 1.f);

        const float px = u * (float)FW - 0.5f;
        const float py = v * (float)FH - 0.5f;
        const float fx0 = floorf(px), fy0 = floorf(py);
        const int x0 = (int)fx0, y0 = (int)fy0;
        const int x1 = x0 + 1,   y1 = y0 + 1;
        const float wx1 = px - fx0, wy1 = py - fy0;
        const float wx0 = 1.f - wx1, wy0 = 1.f - wy1;

        const bool vx0 = (x0 >= 0) && (x0 < FW);
        const bool vx1 = (x1 >= 0) && (x1 < FW);
        const bool vy0 = (y0 >= 0) && (y0 < FH);
        const bool vy1 = (y1 >= 0) && (y1 < FH);
        const int cx0 = min(max(x0, 0), FW - 1), cx1 = min(max(x1, 0), FW - 1);
        const int cy0 = min(max(y0, 0), FH - 1), cy1 = min(max(y1, 0), FH - 1);

        const float w0v = wx0 * wy0 * ((vx0 && vy0) ? 1.f : 0.f);
        const float w1v = wx1 * wy0 * ((vx1 && vy0) ? 1.f : 0.f);
        const float w2v = wx0 * wy1 * ((vx0 && vy1) ? 1.f : 0.f);
        const float w3v = wx1 * wy1 * ((vx1 && vy1) ? 1.f : 0.f);

        const int bx = min(max(x0, 0), FW - 2);
        wTL = ((cx0 == bx)     ? w0v : 0.f) + ((cx1 == bx)     ? w1v : 0.f);
        wTR = ((cx0 == bx + 1) ? w0v : 0.f) + ((cx1 == bx + 1) ? w1v : 0.f);
        wBL = ((cx0 == bx)     ? w2v : 0.f) + ((cx1 == bx)     ? w3v : 0.f);
        wBR = ((cx0 == bx + 1) ? w2v : 0.f) + ((cx1 == bx + 1) ? w3v : 0.f);

        const int base = n * FH * FW;
        iT = (base + cy0 * FW + bx) * CC;
        iB = (base + cy1 * FW + bx) * CC;
    }

    const unsigned long long bal = __ballot(m);
    unsigned balA = (unsigned)(bal & 0xFFFFFFull);
    unsigned balB = (unsigned)((bal >> 32) & 0xFFFFFFull);
    const float cntA = fmaxf((float)__popc(balA), 1.f);
    const float cntB = fmaxf((float)__popc(balB), 1.f);

    float aAx = 0.f, aAy = 0.f, aAz = 0.f, aAw = 0.f;
    float aBx = 0.f, aBy = 0.f, aBz = 0.f, aBw = 0.f;
    const int loff = 4 * lane;

    while (balA | balB) {
        int eA0 = 0, eA1 = 0, eB0 = 32, eB1 = 32;
        float sA0 = 0.f, sA1 = 0.f, sB0 = 0.f, sB1 = 0.f;
        if (balA) {
            eA0 = __builtin_ctz(balA); balA &= balA - 1; sA0 = 1.f;
            if (balA) { eA1 = __builtin_ctz(balA); balA &= balA - 1; sA1 = 1.f; }
            else eA1 = eA0;
        }
        if (balB) {
            eB0 = 32 + __builtin_ctz(balB); balB &= balB - 1; sB0 = 1.f;
            if (balB) { eB1 = 32 + __builtin_ctz(balB); balB &= balB - 1; sB1 = 1.f; }
            else eB1 = eB0;
        }

        const int jTA0 = __builtin_amdgcn_readlane(iT, eA0), jBA0 = __builtin_amdgcn_readlane(iB, eA0);
        const int jTA1 = __builtin_amdgcn_readlane(iT, eA1), jBA1 = __builtin_amdgcn_readlane(iB, eA1);
        const int jTB0 = __builtin_amdgcn_readlane(iT, eB0), jBB0 = __builtin_amdgcn_readlane(iB, eB0);
        const int jTB1 = __builtin_amdgcn_readlane(iT, eB1), jBB1 = __builtin_amdgcn_readlane(iB, eB1);

        const float4 fTA0 = *(const float4*)(feat + jTA0 + loff);
        const float4 fBA0 = *(const float4*)(feat + jBA0 + loff);
        const float4 fTA1 = *(const float4*)(feat + jTA1 + loff);
        const float4 fBA1 = *(const float4*)(feat + jBA1 + loff);
        const float4 fTB0 = *(const float4*)(feat + jTB0 + loff);
        const float4 fBB0 = *(const float4*)(feat + jBB0 + loff);
        const float4 fTB1 = *(const float4*)(feat + jTB1 + loff);
        const float4 fBB1 = *(const float4*)(feat + jBB1 + loff);

        const float wTA0 = sA0 * (lowhalf ? rdlanef(wTL, eA0) : rdlanef(wTR, eA0));
        const float wBA0 = sA0 * (lowhalf ? rdlanef(wBL, eA0) : rdlanef(wBR, eA0));
        const float wTA1 = sA1 * (lowhalf ? rdlanef(wTL, eA1) : rdlanef(wTR, eA1));
        const float wBA1 = sA1 * (lowhalf ? rdlanef(wBL, eA1) : rdlanef(wBR, eA1));
        const float wTB0 = sB0 * (lowhalf ? rdlanef(wTL, eB0) : rdlanef(wTR, eB0));
        const float wBB0 = sB0 * (lowhalf ? rdlanef(wBL, eB0) : rdlanef(wBR, eB0));
        const float wTB1 = sB1 * (lowhalf ? rdlanef(wTL, eB1) : rdlanef(wTR, eB1));
        const float wBB1 = sB1 * (lowhalf ? rdlanef(wBL, eB1) : rdlanef(wBR, eB1));

        aAx += wTA0 * fTA0.x + wBA0 * fBA0.x + wTA1 * fTA1.x + wBA1 * fBA1.x;
        aAy += wTA0 * fTA0.y + wBA0 * fBA0.y + wTA1 * fTA1.y + wBA1 * fBA1.y;
        aAz += wTA0 * fTA0.z + wBA0 * fBA0.z + wTA1 * fTA1.z + wBA1 * fBA1.z;
        aAw += wTA0 * fTA0.w + wBA0 * fBA0.w + wTA1 * fTA1.w + wBA1 * fBA1.w;
        aBx += wTB0 * fTB0.x + wBB0 * fBB0.x + wTB1 * fTB1.x + wBB1 * fBB1.x;
        aBy += wTB0 * fTB0.y + wBB0 * fBB0.y + wTB1 * fTB1.y + wBB1 * fBB1.y;
        aBz += wTB0 * fTB0.z + wBB0 * fBB0.z + wTB1 * fTB1.z + wBB1 * fBB1.z;
        aBw += wTB0 * fTB0.w + wBB0 * fBB0.w + wTB1 * fTB1.w + wBB1 * fBB1.w;
    }

    aAx += __shfl_xor(aAx, 32);  aAy += __shfl_xor(aAy, 32);
    aAz += __shfl_xor(aAz, 32);  aAw += __shfl_xor(aAw, 32);
    aBx += __shfl_xor(aBx, 32);  aBy += __shfl_xor(aBy, 32);
    aBz += __shfl_xor(aBz, 32);  aBw += __shfl_xor(aBw, 32);

    const float inv = lowhalf ? (1.f / cntA) : (1.f / cntB);
    const int   q   = lowhalf ? qA : (qA + 1);
    float4 o;
    o.x = (lowhalf ? aAx : aBx) * inv;
    o.y = (lowhalf ? aAy : aBy) * inv;
    o.z = (lowhalf ? aAz : aBz) * inv;
    o.w = (lowhalf ? aAw : aBw) * inv;
    *(float4*)(out + q * CC + 4 * l32) = o;
}

extern "C" void kernel_launch(void* const* d_in, const int* in_sizes, int n_in,
                              void* d_out, int out_size, void* d_ws, size_t ws_size,
                              hipStream_t stream) {
    const float* feat = (const float*)d_in[0];
    const float* I_   = (const float*)d_in[1];
    const float* E_   = (const float*)d_in[2];
    const float* grid = (const float*)d_in[3];
    float* out        = (float*)d_out;

    // 8 regions x 722 block-slots (max region 38x19); partial regions early-exit
    bev_sample_kernel<<<8 * 722, 128, 0, stream>>>(feat, I_, E_, grid, out);
}